// Round 4
// baseline (14.553 us; speedup 1.0000x reference)
//
#include <hip/hip_runtime.h>

#define NB 256      // batch
#define S  32       // boxes per sample
#define NL 24       // labels

// tie-aware select: keep (va,ia) unless vb strictly greater, or equal with smaller index
#define COMBINE(va, ia, vb, ib) \
    do { if ((vb) > (va) || ((vb) == (va) && (ib) < (ia))) { (va) = (vb); (ia) = (ib); } } while (0)

__global__ __launch_bounds__(512) void layout_metric_kernel(
    const float* __restrict__ pred_left,
    const float* __restrict__ pred_top,
    const float* __restrict__ pred_width,
    const float* __restrict__ pred_height,
    const float* __restrict__ pred_label,
    const int* __restrict__ true_left,
    const int* __restrict__ true_top,
    const int* __restrict__ true_width,
    const int* __restrict__ true_height,
    const int* __restrict__ true_label,
    const int* __restrict__ true_length,
    const int* __restrict__ pred_length,
    float* __restrict__ out)
{
    const int b   = blockIdx.x;
    const int tid = threadIdx.x;

    __shared__ int s_arg[5][S];                      // argmax: l,t,w,h,label
    __shared__ unsigned long long s_xmask[2][S];     // per-box x coverage mask
    __shared__ unsigned int s_meta[2][S];            // valid<<31|top<<12|bot<<6|lab
    __shared__ unsigned long long s_M[2][NL][64];    // label-major per-row masks
    __shared__ int s_cnt[3][NL];                     // ct, cp, inter

    // ---- Phase 1 (pre-barrier, disjoint waves) ----
    if (tid < 256) {
        // waves 0-3: argmax of the four 64-wide tensors, 2 threads/row,
        // 4 vertical chains (depth 8) + tie-aware combine (first-occurrence exact)
        const int type = tid >> 6;
        const int j    = (tid >> 1) & 31;
        const int half = tid & 1;
        const float* base = (type == 0) ? pred_left
                          : (type == 1) ? pred_top
                          : (type == 2) ? pred_width
                                        : pred_height;
        const float4* r4 = (const float4*)(base + ((size_t)b * S + j) * 64) + half * 8;
        float4 bv = r4[0];
        int ix = half * 32 + 0, iy = half * 32 + 1, iz = half * 32 + 2, iw = half * 32 + 3;
        #pragma unroll
        for (int k = 1; k < 8; ++k) {
            const float4 v = r4[k];
            const int o = half * 32 + 4 * k;
            if (v.x > bv.x) { bv.x = v.x; ix = o + 0; }
            if (v.y > bv.y) { bv.y = v.y; iy = o + 1; }
            if (v.z > bv.z) { bv.z = v.z; iz = o + 2; }
            if (v.w > bv.w) { bv.w = v.w; iw = o + 3; }
        }
        float v0 = bv.x; int i0 = ix;
        COMBINE(v0, i0, bv.y, iy);
        float v1 = bv.z; int i1 = iz;
        COMBINE(v1, i1, bv.w, iw);
        COMBINE(v0, i0, v1, i1);
        // merge halves (lanes tid, tid^1 same wave); high indices all > low → strict >
        const float ob = __shfl_xor(v0, 1);
        const int   oi = __shfl_xor(i0, 1);
        if (half == 0) {
            if (ob > v0) i0 = oi;
            s_arg[type][j] = i0;
        }
    } else if (tid < 288) {
        // wave 4 lanes 0-31: label argmax (24-wide)
        const int j = tid - 256;
        const float4* r4 = (const float4*)(pred_label + ((size_t)b * S + j) * NL);
        float4 bv = r4[0];
        int ix = 0, iy = 1, iz = 2, iw = 3;
        #pragma unroll
        for (int k = 1; k < 6; ++k) {
            const float4 v = r4[k];
            const int o = 4 * k;
            if (v.x > bv.x) { bv.x = v.x; ix = o + 0; }
            if (v.y > bv.y) { bv.y = v.y; iy = o + 1; }
            if (v.z > bv.z) { bv.z = v.z; iz = o + 2; }
            if (v.w > bv.w) { bv.w = v.w; iw = o + 3; }
        }
        float v0 = bv.x; int i0 = ix;
        COMBINE(v0, i0, bv.y, iy);
        float v1 = bv.z; int i1 = iz;
        COMBINE(v1, i1, bv.w, iw);
        COMBINE(v0, i0, v1, i1);
        s_arg[4][j] = i0;
    } else if (tid >= 320 && tid < 352) {
        // wave 5 lanes 0-31: true-box setup (independent of argmax)
        const int j   = tid - 320;
        const int l   = true_left  [b * S + j];
        const int t   = true_top   [b * S + j];
        const int w   = true_width [b * S + j];
        const int h   = true_height[b * S + j];
        const int lab = true_label [b * S + j];
        const int len = true_length[b];
        const int r  = min(63, l + w);
        const int bo = min(63, t + h);
        const bool val = (j < len) && (t < bo) && (l < r);
        unsigned long long xm = 0ull;
        if (val) xm = (~0ull << l) & (~0ull >> (63 - r));
        s_xmask[0][j] = xm;
        s_meta[0][j]  = (val ? 0x80000000u : 0u) |
                        ((unsigned)t << 12) | ((unsigned)bo << 6) | (unsigned)lab;
    }
    __syncthreads();

    // ---- Phase 2: pred-box setup (needs s_arg) ----
    if (tid < S) {
        const int j   = tid;
        const int l   = s_arg[0][j];
        const int t   = s_arg[1][j];
        const int w   = s_arg[2][j];
        const int h   = s_arg[3][j];
        const int lab = s_arg[4][j];
        const int len = pred_length[b];
        const int r  = min(63, l + w);
        const int bo = min(63, t + h);
        const bool val = (j < len) && (t < bo) && (l < r);
        unsigned long long xm = 0ull;
        if (val) xm = (~0ull << l) & (~0ull >> (63 - r));
        s_xmask[1][j] = xm;
        s_meta[1][j]  = (val ? 0x80000000u : 0u) |
                        ((unsigned)t << 12) | ((unsigned)bo << 6) | (unsigned)lab;
    }
    __syncthreads();

    // ---- Phase 3: painter's sweep → 5 register bit-planes → per-label masks ----
    if (tid < 128) {
        const int m = tid >> 6;
        const int y = tid & 63;
        unsigned long long rem = ~0ull;
        unsigned long long pl0 = 0, pl1 = 0, pl2 = 0, pl3 = 0, pl4 = 0;
        #pragma unroll
        for (int j = S - 1; j >= 0; --j) {
            const unsigned int md = s_meta[m][j];   // wave-uniform
            if (md & 0x80000000u) {
                const int top = (md >> 12) & 63;
                const int bot = (md >> 6)  & 63;
                const unsigned long long cov =
                    (top <= y && y <= bot) ? (s_xmask[m][j] & rem) : 0ull;
                rem &= ~cov;
                const unsigned lab = md & 31;       // wave-uniform
                if (lab & 1u)  pl0 |= cov;
                if (lab & 2u)  pl1 |= cov;
                if (lab & 4u)  pl2 |= cov;
                if (lab & 8u)  pl3 |= cov;
                if (lab & 16u) pl4 |= cov;
            }
        }
        // uncovered pixels: label 0 == all planes 0 → already correct
        const unsigned long long n0 = ~pl0, n1 = ~pl1, n2 = ~pl2, n3 = ~pl3, n4 = ~pl4;
        #pragma unroll
        for (int L = 0; L < NL; ++L) {
            const unsigned long long mk = ((L & 1)  ? pl0 : n0)
                                        & ((L & 2)  ? pl1 : n1)
                                        & ((L & 4)  ? pl2 : n2)
                                        & ((L & 8)  ? pl3 : n3)
                                        & ((L & 16) ? pl4 : n4);
            s_M[m][L][y] = mk;          // plain store, covers all entries
        }
    }
    __syncthreads();

    // ---- Phase 4: popcount + 8-lane shuffle reduce (no atomics) ----
    if (tid < 8 * NL) {
        const int L  = tid >> 3;
        const int rg = tid & 7;
        const ulonglong2* pt = (const ulonglong2*)&s_M[0][L][rg * 8];
        const ulonglong2* pp = (const ulonglong2*)&s_M[1][L][rg * 8];
        int ct = 0, cp = 0, ci = 0;
        #pragma unroll
        for (int i = 0; i < 4; ++i) {
            const ulonglong2 a = pt[i];
            const ulonglong2 c = pp[i];
            ct += __popcll(a.x) + __popcll(a.y);
            cp += __popcll(c.x) + __popcll(c.y);
            ci += __popcll(a.x & c.x) + __popcll(a.y & c.y);
        }
        #pragma unroll
        for (int d = 1; d < 8; d <<= 1) {
            ct += __shfl_xor(ct, d);
            cp += __shfl_xor(cp, d);
            ci += __shfl_xor(ci, d);
        }
        if (rg == 0) { s_cnt[0][L] = ct; s_cnt[1][L] = cp; s_cnt[2][L] = ci; }
    }
    __syncthreads();

    // ---- Phase 5: wave-parallel final metrics ----
    if (tid < 64) {
        float it_p = 0.f, ws_p = 0.f, wi_p = 0.f;
        if (tid < NL) {
            const int ct = s_cnt[0][tid];
            const int cp = s_cnt[1][tid];
            const int ci = s_cnt[2][tid];
            const int un = ct + cp - ci;
            it_p = (float)ci;
            if (un > 0) {
                ws_p = 1.f;
                wi_p = (float)ci / ((float)un + 1e-9f);
            }
        }
        #pragma unroll
        for (int m = 32; m >= 1; m >>= 1) {
            it_p += __shfl_xor(it_p, m);
            ws_p += __shfl_xor(ws_p, m);
            wi_p += __shfl_xor(wi_p, m);
        }
        if (tid == 0) {
            out[b]      = it_p / 4096.0f;   // acc
            out[NB + b] = wi_p / ws_p;      // miou
        }
    }
}

extern "C" void kernel_launch(void* const* d_in, const int* in_sizes, int n_in,
                              void* d_out, int out_size, void* d_ws, size_t ws_size,
                              hipStream_t stream) {
    const float* pred_left   = (const float*)d_in[0];
    const float* pred_top    = (const float*)d_in[1];
    const float* pred_width  = (const float*)d_in[2];
    const float* pred_height = (const float*)d_in[3];
    const float* pred_label  = (const float*)d_in[4];
    const int*   true_left   = (const int*)d_in[5];
    const int*   true_top    = (const int*)d_in[6];
    const int*   true_width  = (const int*)d_in[7];
    const int*   true_height = (const int*)d_in[8];
    const int*   true_label  = (const int*)d_in[9];
    const int*   true_length = (const int*)d_in[10];
    const int*   pred_length = (const int*)d_in[11];
    float* out = (float*)d_out;

    layout_metric_kernel<<<NB, 512, 0, stream>>>(
        pred_left, pred_top, pred_width, pred_height, pred_label,
        true_left, true_top, true_width, true_height, true_label,
        true_length, pred_length, out);
}